// Round 5
// baseline (363.924 us; speedup 1.0000x reference)
//
#include <hip/hip_runtime.h>
#include <math.h>

// B=4,S=4096 -> NTOK=16384; D=2048; E=8; R=16; K=2; SCALING=1
// Inputs fp32; d_out fp32: out[16384][2048] then probs[16384][8].
// ws layout (bf16/ushort): Wt[160][2048] | Bm2[2048][128]
//   Wt rows: 0-7 gate hi, 8-15 zero, 16-143 A (expert e rows 16+e*16..),
//            144-151 gate lo residual, 152-159 zero. Plain row-major.
// v5: barrier-free K-loop. Each wave loads W fragments (L2-hot) and its own
// x fragments direct to registers; hi/lo bf16 split in-register. No LDS, no
// __syncthreads in the K-loop -> waves fully decoupled, loads pipeline freely.
// Epilogue (3 barriers): Cs gather -> softmax/top2 -> gelu -> LDS hm -> combine
// (swapped-operand MFMA, float4 stores).
#define NTOK 16384
#define DIM  2048
#define NEXP 8
#define RANK 16

typedef unsigned short ushort_t;
typedef unsigned int   uint_t;
typedef __attribute__((ext_vector_type(8))) short bf16x8;
typedef __attribute__((ext_vector_type(4))) float f32x4;

__device__ __forceinline__ ushort_t f2bf(float f) {
  union { float f; uint_t u; } v; v.f = f;
  uint_t r = (v.u + 0x7FFFu + ((v.u >> 16) & 1u)) >> 16;
  return (ushort_t)r;
}
__device__ __forceinline__ float bf2f(ushort_t s) {
  union { uint_t u; float f; } v; v.u = ((uint_t)s) << 16;
  return v.f;
}

__device__ __forceinline__ bf16x8 cvt_hi(float4 a, float4 b) {
  ushort_t h[8];
  h[0] = f2bf(a.x); h[1] = f2bf(a.y); h[2] = f2bf(a.z); h[3] = f2bf(a.w);
  h[4] = f2bf(b.x); h[5] = f2bf(b.y); h[6] = f2bf(b.z); h[7] = f2bf(b.w);
  return *(const bf16x8*)h;
}
__device__ __forceinline__ bf16x8 cvt_lo(float4 a, float4 b, bf16x8 hi) {
  ushort_t l[8];
  l[0] = f2bf(a.x - bf2f((ushort_t)hi[0]));
  l[1] = f2bf(a.y - bf2f((ushort_t)hi[1]));
  l[2] = f2bf(a.z - bf2f((ushort_t)hi[2]));
  l[3] = f2bf(a.w - bf2f((ushort_t)hi[3]));
  l[4] = f2bf(b.x - bf2f((ushort_t)hi[4]));
  l[5] = f2bf(b.y - bf2f((ushort_t)hi[5]));
  l[6] = f2bf(b.z - bf2f((ushort_t)hi[6]));
  l[7] = f2bf(b.w - bf2f((ushort_t)hi[7]));
  return *(const bf16x8*)l;
}

// ---------------- K0: weight prep (fp32 -> bf16, flat layouts) ----------------
__global__ __launch_bounds__(256) void k0_prep(
    const float* __restrict__ gW, const float* __restrict__ A,
    const float* __restrict__ Bm,
    ushort_t* __restrict__ Wt, ushort_t* __restrict__ Bm2) {
  int b = blockIdx.x, t = threadIdx.x;
  if (b < 1280) {                       // Wt: 160 rows x 2048 cols
    int idx = b * 256 + t;
    int r = idx >> 11, d = idx & 2047;
    float v;
    if (r < 8)        v = gW[r * 2048 + d];
    else if (r < 16)  v = 0.f;
    else if (r < 144) v = A[(size_t)(r - 16) * 2048 + d];
    else if (r < 152) { float g = gW[(r - 144) * 2048 + d]; v = g - bf2f(f2bf(g)); }
    else              v = 0.f;
    Wt[(size_t)r * 2048 + d] = f2bf(v);
  } else {                              // Bm2[2048][128]: Bm2[d][e*16+r]=Bm[e][d][r]
    int idx = (b - 1280) * 256 + t;     // 0..262143
    int dd = idx >> 7, c = idx & 127, e = c >> 4, rr = c & 15;
    Bm2[idx] = f2bf(Bm[((size_t)e * 2048 + dd) * 16 + rr]);
  }
}

// ---------------- K1: fused gate + h + combine (512 thr, barrier-free K) ----
__global__ __launch_bounds__(512, 4) void k1_fused(
    const float* __restrict__ x, const float* __restrict__ gate_b,
    const ushort_t* __restrict__ Wt, const ushort_t* __restrict__ Bm2,
    float* __restrict__ out, float* __restrict__ probs) {
  __shared__ float Cs[32][152];
  __shared__ __align__(16) ushort_t hm_s[32][128];
  __shared__ int sel0s[32], sel1s[32];

  const int t = threadIdx.x;
  const int lane = t & 63, wave = t >> 6;       // 8 waves
  const int l15 = lane & 15, q = lane >> 4;
  const int mt = wave & 1;        // M-tile (16 tokens)
  const int ng = wave >> 1;       // N-group: tiles {0g,1},{2,3},{4,5},{6,7,8}
  const int ntiles = (ng == 3) ? 3 : 2;
  const int tok0 = blockIdx.x * 32;
  const int tok  = tok0 + mt * 16 + l15;

  // W row bases (bf16 rows of Wt), column offset q*8 folded in
  const int rb0 = ng * 32;                       // also the Cs column base
  const ushort_t* w0 = Wt + (size_t)(rb0 + l15) * DIM + q * 8;
  const ushort_t* w1 = Wt + (size_t)(rb0 + 16 + l15) * DIM + q * 8;
  // third fragment: ng0 -> gate-lo rows 144+, ng3 -> tile 8 rows 128+
  const ushort_t* w2 = Wt + (size_t)(((ng == 0) ? 144 : 128) + l15) * DIM + q * 8;
  const float* xr = x + (size_t)tok * DIM + q * 8;

  f32x4 acc[3];
  #pragma unroll
  for (int i = 0; i < 3; ++i) acc[i] = (f32x4)0.f;

  for (int ch = 0; ch < 32; ++ch) {
    const int k0c = ch * 64;
    // ---- x fragments (2 k-steps x 8 fp32), direct from global ----
    float4 xa = *(const float4*)(xr + k0c);
    float4 xb = *(const float4*)(xr + k0c + 4);
    float4 xc = *(const float4*)(xr + k0c + 32);
    float4 xd = *(const float4*)(xr + k0c + 36);
    // ---- W fragments, direct from L2-hot Wt ----
    bf16x8 wA0 = *(const bf16x8*)(w0 + k0c);
    bf16x8 wA1 = *(const bf16x8*)(w0 + k0c + 32);
    bf16x8 wB0 = *(const bf16x8*)(w1 + k0c);
    bf16x8 wB1 = *(const bf16x8*)(w1 + k0c + 32);

    bf16x8 ah0 = cvt_hi(xa, xb), ah1 = cvt_hi(xc, xd);

    if (ng == 0) {
      bf16x8 wC0 = *(const bf16x8*)(w2 + k0c);
      bf16x8 wC1 = *(const bf16x8*)(w2 + k0c + 32);
      bf16x8 al0 = cvt_lo(xa, xb, ah0), al1 = cvt_lo(xc, xd, ah1);
      // gate tile (hi/lo corrected) + tile 1
      acc[0] = __builtin_amdgcn_mfma_f32_16x16x32_bf16(ah0, wA0, acc[0], 0, 0, 0);
      acc[0] = __builtin_amdgcn_mfma_f32_16x16x32_bf16(al0, wA0, acc[0], 0, 0, 0);
      acc[0] = __builtin_amdgcn_mfma_f32_16x16x32_bf16(ah0, wC0, acc[0], 0, 0, 0);
      acc[1] = __builtin_amdgcn_mfma_f32_16x16x32_bf16(ah0, wB0, acc[1], 0, 0, 0);
      acc[0] = __builtin_amdgcn_mfma_f32_16x16x32_bf16(ah1, wA1, acc[0], 0, 0, 0);
      acc[0] = __builtin_amdgcn_mfma_f32_16x16x32_bf16(al1, wA1, acc[0], 0, 0, 0);
      acc[0] = __builtin_amdgcn_mfma_f32_16x16x32_bf16(ah1, wC1, acc[0], 0, 0, 0);
      acc[1] = __builtin_amdgcn_mfma_f32_16x16x32_bf16(ah1, wB1, acc[1], 0, 0, 0);
    } else if (ng == 3) {
      bf16x8 wC0 = *(const bf16x8*)(w2 + k0c);
      bf16x8 wC1 = *(const bf16x8*)(w2 + k0c + 32);
      acc[0] = __builtin_amdgcn_mfma_f32_16x16x32_bf16(ah0, wA0, acc[0], 0, 0, 0);
      acc[1] = __builtin_amdgcn_mfma_f32_16x16x32_bf16(ah0, wB0, acc[1], 0, 0, 0);
      acc[2] = __builtin_amdgcn_mfma_f32_16x16x32_bf16(ah0, wC0, acc[2], 0, 0, 0);
      acc[0] = __builtin_amdgcn_mfma_f32_16x16x32_bf16(ah1, wA1, acc[0], 0, 0, 0);
      acc[1] = __builtin_amdgcn_mfma_f32_16x16x32_bf16(ah1, wB1, acc[1], 0, 0, 0);
      acc[2] = __builtin_amdgcn_mfma_f32_16x16x32_bf16(ah1, wC1, acc[2], 0, 0, 0);
    } else {
      acc[0] = __builtin_amdgcn_mfma_f32_16x16x32_bf16(ah0, wA0, acc[0], 0, 0, 0);
      acc[1] = __builtin_amdgcn_mfma_f32_16x16x32_bf16(ah0, wB0, acc[1], 0, 0, 0);
      acc[0] = __builtin_amdgcn_mfma_f32_16x16x32_bf16(ah1, wA1, acc[0], 0, 0, 0);
      acc[1] = __builtin_amdgcn_mfma_f32_16x16x32_bf16(ah1, wB1, acc[1], 0, 0, 0);
    }
  }

  // ---- write C tiles to LDS (col = lane&15, row = quad*4+reg) ----
  #pragma unroll
  for (int i = 0; i < 3; ++i) {
    if (i < ntiles) {
      #pragma unroll
      for (int r = 0; r < 4; ++r)
        Cs[mt * 16 + q * 4 + r][rb0 + i * 16 + l15] = acc[i][r];
    }
  }
  __syncthreads();

  // ---- softmax + top-2 per token ----
  if (t < 32) {
    int m = t;
    float lg[NEXP];
    #pragma unroll
    for (int e = 0; e < NEXP; ++e) lg[e] = Cs[m][e] + gate_b[e];
    float mx = lg[0];
    #pragma unroll
    for (int e = 1; e < NEXP; ++e) mx = fmaxf(mx, lg[e]);
    float ex[NEXP], s = 0.f;
    #pragma unroll
    for (int e = 0; e < NEXP; ++e) { ex[e] = __expf(lg[e] - mx); s += ex[e]; }
    float inv = 1.f / s;
    float4 p0 = make_float4(ex[0] * inv, ex[1] * inv, ex[2] * inv, ex[3] * inv);
    float4 p1 = make_float4(ex[4] * inv, ex[5] * inv, ex[6] * inv, ex[7] * inv);
    float* pp = probs + (size_t)(tok0 + m) * NEXP;
    *(float4*)pp = p0; *(float4*)(pp + 4) = p1;
    int i0 = 0;
    #pragma unroll
    for (int e = 1; e < NEXP; ++e) if (lg[e] > lg[i0]) i0 = e;
    int i1 = (i0 == 0) ? 1 : 0;
    #pragma unroll
    for (int e = 0; e < NEXP; ++e) if (e != i0 && lg[e] > lg[i1]) i1 = e;
    sel0s[m] = i0; sel1s[m] = i1;
  }
  __syncthreads();

  // ---- gelu + mask -> hm_s (LDS, granule-XOR-swizzled rows of 128) ----
  if (t < 256) {
    int m = t >> 3, e = t & 7;
    int on = (e == sel0s[m]) | (e == sel1s[m]);
    ushort_t ov[16];
    #pragma unroll
    for (int r = 0; r < RANK; ++r) {
      float v = Cs[m][16 + e * 16 + r];
      float g = on ? (0.5f * v * (1.f + erff(v * 0.70710678118654752f))) : 0.f;
      ov[r] = f2bf(g);
    }
    int g0 = (2 * e) ^ (m & 7), g1 = (2 * e + 1) ^ (m & 7);
    *(uint4*)&hm_s[m][g0 * 8] = *(const uint4*)&ov[0];
    *(uint4*)&hm_s[m][g1 * 8] = *(const uint4*)&ov[8];
  }
  __syncthreads();

  // ---- combine: out[32][2048] = Hm_lds . Bm2^T; wave w owns cols w*256.. ----
  {
    bf16x8 af[2][4];
    #pragma unroll
    for (int m2 = 0; m2 < 2; ++m2) {
      int tk = m2 * 16 + l15;
      #pragma unroll
      for (int kk = 0; kk < 4; ++kk)
        af[m2][kk] = *(const bf16x8*)&hm_s[tk][(((kk * 4 + q) ^ (tk & 7)) << 3)];
    }

    const int ncol0 = wave * 256;
    const ushort_t* bp = Bm2 + (size_t)(ncol0 + l15) * 128 + q * 8;

    auto loadB = [&](bf16x8* dst, int i) {
      #pragma unroll
      for (int k = 0; k < 4; ++k)
        dst[k] = *(const bf16x8*)(bp + (size_t)i * 2048 + k * 32);   // 16 rows/tile
    };
    auto comp = [&](const bf16x8* bb, int i) {
      #pragma unroll
      for (int m2 = 0; m2 < 2; ++m2) {
        f32x4 c = (f32x4)0.f;
        #pragma unroll
        for (int k = 0; k < 4; ++k)   // swapped operands -> transposed C layout
          c = __builtin_amdgcn_mfma_f32_16x16x32_bf16(bb[k], af[m2][k], c, 0, 0, 0);
        *(f32x4*)&out[(size_t)(tok0 + m2 * 16 + l15) * DIM + ncol0 + i * 16 + q * 4] = c;
      }
    };

    bf16x8 bA[4], bB[4];
    loadB(bA, 0);
    #pragma unroll
    for (int ii = 0; ii < 8; ++ii) {         // 16 tiles x 16 cols = 256 cols
      loadB(bB, 2 * ii + 1);
      comp(bA, 2 * ii);
      if (ii < 7) loadB(bA, 2 * ii + 2);
      comp(bB, 2 * ii + 1);
    }
  }
}

extern "C" void kernel_launch(void* const* d_in, const int* in_sizes, int n_in,
                              void* d_out, int out_size, void* d_ws, size_t ws_size,
                              hipStream_t stream) {
  const float* x      = (const float*)d_in[0];
  const float* gate_W = (const float*)d_in[1];
  const float* gate_b = (const float*)d_in[2];
  const float* A      = (const float*)d_in[3];
  const float* Bm     = (const float*)d_in[4];

  float* out   = (float*)d_out;                 // [NTOK][DIM]
  float* probs = out + (size_t)NTOK * DIM;      // [NTOK][NEXP]

  ushort_t* Wt  = (ushort_t*)d_ws;              // [160][2048]
  ushort_t* Bm2 = Wt + 160 * 2048;              // [2048][128]

  k0_prep<<<dim3(2304), dim3(256), 0, stream>>>(gate_W, A, Bm, Wt, Bm2);
  k1_fused<<<dim3(NTOK / 32), dim3(512), 0, stream>>>(x, gate_b, Wt, Bm2, out, probs);
}